// Round 1
// baseline (59.898 us; speedup 1.0000x reference)
//
#include <hip/hip_runtime.h>

// DiscreteHazardLoss: loss_i = -( sum_{j<t_i} log(1-sigmoid(x_ij)+eps)
//                                 + (ev_i ? log(sigmoid(x_it)+eps)
//                                         : log(1-sigmoid(x_it)+eps)) )
// out = mean_i loss_i.
// Identities (eps=1e-7 negligible for |x| <~ 6):
//   log(1-sigmoid(x)) = -softplus(x) = -log(1+exp(x))
//   log(sigmoid(x))   =  x - softplus(x)
// So contribution for j<=t is -softplus(x_j), plus +x_t iff (j==t && ev).
// Final out = -(total_sum)/B.

constexpr int T_BINS        = 32;
constexpr int BLOCK         = 256;
constexpr int LANES_PER_ROW = 8;                       // 8 lanes x float4 = 32 cols
constexpr int ROWS_PER_ITER = BLOCK / LANES_PER_ROW;   // 32 rows per block per iter
constexpr int NBLOCKS       = 2048;

// time_bins is declared int64 in the reference but JAX (no x64) usually
// delivers int32. Detect: int64 LE with values in [0,32) => every odd int32
// word is 0. P(false positive on real int32 data) = (1/32)^256 ~ 0.
__global__ void dhl_detect_i64(const int* __restrict__ tb, int* __restrict__ flag) {
    __shared__ int s_any;
    if (threadIdx.x == 0) s_any = 0;
    __syncthreads();
    int v = tb[2 * threadIdx.x + 1];
    if (v != 0) atomicOr(&s_any, 1);
    __syncthreads();
    if (threadIdx.x == 0) *flag = (s_any == 0) ? 1 : 0;   // 1 => int64
}

__global__ __launch_bounds__(BLOCK) void dhl_main(
    const float4* __restrict__ logits4,   // [B * 8] float4
    const int*    __restrict__ tb,        // int32 view of time_bins
    const int*    __restrict__ ev,        // [B]
    const int*    __restrict__ flag64,    // 0 -> int32, 1 -> int64 (stride 2)
    float*        __restrict__ partials,  // [gridDim.x]
    int nrows, int rows_per_block)
{
    const int shift = *flag64;            // uniform
    const int tid   = threadIdx.x;
    const int lane8 = tid & (LANES_PER_ROW - 1);
    const int rloc  = tid >> 3;
    const int j0    = lane8 * 4;
    const long long rbase = (long long)blockIdx.x * rows_per_block;

    float acc = 0.0f;
    for (int i = 0; i < rows_per_block; i += ROWS_PER_ITER) {
        long long row = rbase + i + rloc;
        if (row < nrows) {
            float4 v = logits4[row * LANES_PER_ROW + lane8];
            int t = tb[row << shift];
            t = min(max(t, 0), T_BINS - 1);
            const int e = ev[row];
            float xs[4] = {v.x, v.y, v.z, v.w};
            #pragma unroll
            for (int c = 0; c < 4; ++c) {
                float x = xs[c];
                float L = __logf(1.0f + __expf(x));   // softplus(x)
                int j = j0 + c;
                if (j <= t) acc -= L;
                if (j == t && e == 1) acc += x;
            }
        }
    }

    // wave (64-lane) reduce
    #pragma unroll
    for (int off = 32; off > 0; off >>= 1)
        acc += __shfl_down(acc, off, 64);

    __shared__ float sw[BLOCK / 64];
    if ((tid & 63) == 0) sw[tid >> 6] = acc;
    __syncthreads();
    if (tid == 0) {
        float s = 0.0f;
        #pragma unroll
        for (int w = 0; w < BLOCK / 64; ++w) s += sw[w];
        partials[blockIdx.x] = s;
    }
}

__global__ __launch_bounds__(BLOCK) void dhl_finalize(
    const float* __restrict__ partials, int n, float* __restrict__ out, float scale)
{
    const int tid = threadIdx.x;
    float acc = 0.0f;
    for (int i = tid; i < n; i += BLOCK) acc += partials[i];
    #pragma unroll
    for (int off = 32; off > 0; off >>= 1)
        acc += __shfl_down(acc, off, 64);
    __shared__ float sw[BLOCK / 64];
    if ((tid & 63) == 0) sw[tid >> 6] = acc;
    __syncthreads();
    if (tid == 0) {
        float s = 0.0f;
        #pragma unroll
        for (int w = 0; w < BLOCK / 64; ++w) s += sw[w];
        out[0] = s * scale;   // scale = -1/B
    }
}

extern "C" void kernel_launch(void* const* d_in, const int* in_sizes, int n_in,
                              void* d_out, int out_size, void* d_ws, size_t ws_size,
                              hipStream_t stream) {
    const float4* logits4 = (const float4*)d_in[0];
    const int*    tb      = (const int*)d_in[1];
    const int*    ev      = (const int*)d_in[2];
    float*        out     = (float*)d_out;
    const int B = in_sizes[1];   // element count of time_bins = rows

    int*   flag     = (int*)d_ws;
    float* partials = (float*)((char*)d_ws + 256);

    int rows_per_block = (B + NBLOCKS - 1) / NBLOCKS;
    rows_per_block = ((rows_per_block + ROWS_PER_ITER - 1) / ROWS_PER_ITER) * ROWS_PER_ITER;
    int nblocks = (B + rows_per_block - 1) / rows_per_block;

    dhl_detect_i64<<<1, BLOCK, 0, stream>>>(tb, flag);
    dhl_main<<<nblocks, BLOCK, 0, stream>>>(logits4, tb, ev, flag, partials, B, rows_per_block);
    dhl_finalize<<<1, BLOCK, 0, stream>>>(partials, nblocks, out, -1.0f / (float)B);
}